// Round 9
// baseline (524.872 us; speedup 1.0000x reference)
//
#include <hip/hip_runtime.h>
#include <hip/hip_bf16.h>

// irreps: node = 64x0e + 32x1o (160 f32), edge = 8x0e + 8x1o (32 f32)
// hidden = 96x0e + 32x1o ; agg row = 96 scalars + 32*3 vectors = 192 f32
constexpr int kNodes = 10000;
constexpr int kEdges = 100000;

constexpr float INV_SQRT3    = 0.57735026918962576f;
constexpr float INV_SQRT768  = 0.036084391824351615f;  // msg fan
constexpr float INV_SQRT7168 = 0.011811389781538352f;  // upd scalar fan
constexpr float INV_SQRT5120 = 0.013975424859373686f;  // upd vector fan
constexpr float INV_SQRT32   = 0.17677669529663687f;

// d_ws: ONLY the f32 agg accumulator [10000][192] = 7,680,000 B (proven safe size).
// d_out (6.4 MB) holds prepped bf16 weights + edge-sort scratch until the final copy:
constexpr size_t MSGW_OFF  = 0;         // 24 x [128][32] bf16 = 196,608 B
constexpr size_t UPDW1_OFF = 196608;    // 224 x [96][32]      = 1,376,256 B
constexpr size_t UPDW2_OFF = 1572864;   // 160 x [32][32]      = 327,680 B
constexpr size_t MLINS_OFF = 1900544;   // [96][64]            = 12,288 B
constexpr size_t MLINV_OFF = 1912832;   // [32][32]            = 2,048 B
constexpr size_t ULINS_OFF = 1914880;   // [64][64]            = 8,192 B
constexpr size_t ULINV_OFF = 1923072;   // [32][32]            = 2,048 B
constexpr size_t CNT_OFF   = 1926144;   // 10000 int (per-node edge count)
constexpr size_t CUR_OFF   = 1967104;   // 10000 int (scatter cursors)
constexpr size_t PERM_OFF  = 2008064;   // 100000 int (dest-sorted edge ids), end 2,408,064 < 6.4MB

typedef __attribute__((ext_vector_type(8))) short bf8;  // 8 bf16 (4 VGPR) MFMA operand
typedef __attribute__((ext_vector_type(4))) float f4;   // MFMA accumulator
union BF { bf8 v; short s[8]; unsigned u[4]; };

__device__ __forceinline__ short f2bf(float f) {   // RNE f32->bf16 (cold paths)
    union { float f; unsigned u; } c; c.f = f;
    unsigned r = c.u + 0x7fffu + ((c.u >> 16) & 1u);
    return (short)(r >> 16);
}
__device__ __forceinline__ unsigned pk2(float lo, float hi) {  // v_cvt_pk_bf16_f32
    union { __hip_bfloat162 h; unsigned u; } c;
    c.h = __float22bfloat162_rn(make_float2(lo, hi));
    return c.u;
}
__device__ __forceinline__ f4 mfma16(bf8 a, bf8 b, f4 c) {
    return __builtin_amdgcn_mfma_f32_16x16x32_bf16(a, b, c, 0, 0, 0);
}
__device__ __forceinline__ bf8 ldB(const char* p) {  // direct L2-served B-fragment
    return *(const bf8*)p;
}
__device__ __forceinline__ float fsig(float x) { return 1.0f / (1.0f + __expf(-x)); }

// ================= prep: scale + transpose + reorder weights to bf16 (into d_out) ==========
__global__ void prep_kernel(
    const float* __restrict__ Wmss, const float* __restrict__ Wmvv,
    const float* __restrict__ Wmsv, const float* __restrict__ Wmvs,
    const float* __restrict__ Wlms, const float* __restrict__ Wlmv,
    const float* __restrict__ Wuss, const float* __restrict__ Wuvv,
    const float* __restrict__ Wusv, const float* __restrict__ Wuvs,
    const float* __restrict__ Wlus, const float* __restrict__ Wluv,
    char* __restrict__ wout)
{
    int i = blockIdx.x * 256 + threadIdx.x;
    float v;
    short* dst;
    if (i < 98304) {                        // msgW: [24][128][32]
        dst = (short*)(wout + MSGW_OFF) + i;
        int t = i >> 12, q = i & 4095, r = q >> 5, c = q & 31;
        int k = t * 32 + c;
        if (r < 96) {                       // W1: k<512 ss (k=u*8+v); else vv natural
            v = (k < 512 ? Wmss[k * 96 + r]
                         : Wmvv[(k - 512) * 96 + r] * INV_SQRT3) * INV_SQRT768;
        } else {                            // W2: k<512 sv REORDERED k=v*64+u; else vs natural
            int n2 = r - 96;
            if (k < 512) { int u = k & 63, vv = k >> 6; v = Wmsv[(u * 8 + vv) * 32 + n2] * INV_SQRT768; }
            else         { v = Wmvs[(k - 512) * 32 + n2] * INV_SQRT768; }
        }
    } else if (i < 786432) {                // updW1: [224][96][32]
        int j = i - 98304;
        dst = (short*)(wout + UPDW1_OFF) + j;
        int t = j / 3072, q = j % 3072, r = q >> 5, c = q & 31;
        int k = t * 32 + c;
        if (k < 6144) { int u = k & 63, vv = k >> 6;              // ss REORDERED k=v*64+u
            v = Wuss[(u * 96 + vv) * 96 + r] * INV_SQRT7168; }
        else { int r2 = k - 6144; int u = r2 & 31, vv = r2 >> 5;  // vv REORDERED k=v*32+u
            v = Wuvv[(u * 32 + vv) * 96 + r] * (INV_SQRT3 * INV_SQRT7168); }
    } else if (i < 950272) {                // updW2: [160][32][32]
        int j = i - 786432;
        dst = (short*)(wout + UPDW2_OFF) + j;
        int t = j >> 10, q = j & 1023, r = q >> 5, c = q & 31;
        int k = t * 32 + c;
        if (k < 2048) { int u = k & 63, vv = k >> 6;              // sv REORDERED k=v*64+u
            v = Wusv[(u * 32 + vv) * 32 + r] * INV_SQRT5120; }
        else { int r2 = k - 2048;                                  // vs natural u*96+v
            v = Wuvs[r2 * 32 + r] * INV_SQRT5120; }
    } else if (i < 956416) {                // mlin_s: [96][64]
        int j = i - 950272;
        dst = (short*)(wout + MLINS_OFF) + j;
        int n = j >> 6, kk = j & 63;
        v = Wlms[kk * 96 + n] * 0.125f;
    } else if (i < 957440) {                // mlin_v: [32][32]
        int j = i - 956416;
        dst = (short*)(wout + MLINV_OFF) + j;
        int n = j >> 5, kk = j & 31;
        v = Wlmv[kk * 32 + n] * INV_SQRT32;
    } else if (i < 961536) {                // ulin_s: [64][64]
        int j = i - 957440;
        dst = (short*)(wout + ULINS_OFF) + j;
        int n = j >> 6, kk = j & 63;
        v = Wlus[kk * 64 + n] * 0.125f;
    } else if (i < 962560) {                // ulin_v: [32][32]
        int j = i - 961536;
        dst = (short*)(wout + ULINV_OFF) + j;
        int n = j >> 5, kk = j & 31;
        v = Wluv[kk * 32 + n] * INV_SQRT32;
    } else return;
    *dst = f2bf(v);
}

// ================= edge sort by destination row: histogram -> scan -> scatter =========
__global__ __launch_bounds__(256) void hist_kernel(const int* __restrict__ eidx,
                                                   int* __restrict__ cnt)
{
    int e = blockIdx.x * 256 + threadIdx.x;
    if (e < kEdges) atomicAdd(&cnt[eidx[e]], 1);
}

__global__ __launch_bounds__(256) void scan_kernel(const int* __restrict__ cnt,
                                                   int* __restrict__ cursor)
{   // single block: exclusive prefix over 10000 counts -> scatter cursors
    __shared__ int psum[256];
    const int t = threadIdx.x, base = t * 40;      // 256*40 = 10240 >= 10000
    int s = 0;
    for (int j = 0; j < 40; ++j) { int idx = base + j; if (idx < kNodes) s += cnt[idx]; }
    psum[t] = s;
    __syncthreads();
    if (t == 0) { int a = 0; for (int i = 0; i < 256; ++i) { int x = psum[i]; psum[i] = a; a += x; } }
    __syncthreads();
    int run = psum[t];
    for (int j = 0; j < 40; ++j) {
        int idx = base + j;
        if (idx < kNodes) { cursor[idx] = run; run += cnt[idx]; }
    }
}

__global__ __launch_bounds__(256) void scatter_kernel(const int* __restrict__ eidx,
                                                      int* __restrict__ cursor,
                                                      int* __restrict__ perm)
{
    int e = blockIdx.x * 256 + threadIdx.x;
    if (e < kEdges) {
        int p = atomicAdd(&cursor[eidx[e]], 1);
        perm[p] = e;
    }
}

// ================= message kernel: 32 DEST-SORTED edges/block, 4 waves, MFMA ==========
// Block-local LDS aggregation (ds_add_f32) -> one coalesced atomic flush per distinct
// destination row (~4/block) instead of 192 global atomics per edge.
__global__ __launch_bounds__(256, 3) void msg_kernel(
    const float* __restrict__ nf, const float* __restrict__ ea,
    const int* __restrict__ eidx, const char* __restrict__ wout,
    float* __restrict__ agg)
{
    __shared__ char pool[42752];
    float* nf_sh   = (float*)pool;                 // [32][164] 20992B   (K-loop phase)
    float* ea_sh   = (float*)(pool + 20992);       // [32][36]  4608B
    float* aggloc  = (float*)pool;                 // overlay: [32][192] 24576B (epilogue)
    int*   row_sh  = (int*)  (pool + 25600);       // [32]
    int*   rank_sh = (int*)  (pool + 25728);       // [32]  first-occurrence index of row
    float* gat     = (float*)(pool + 25856);       // [32][36]  4608B
    short* silu_s  = (short*)(pool + 30464);       // [32][72]  4608B
    short* pv_s    = (short*)(pool + 35072);       // [96][40]  7680B -> 42752B => 3 blocks/CU

    const int t = threadIdx.x, w = t >> 6, lane = t & 63;
    const int l15 = lane & 15, lg = lane >> 4;     // lg in [0,4): k-group
    const int eblk = blockIdx.x * 32;

    const char* msgW = wout + MSGW_OFF;
    const int*  perm = (const int*)(wout + PERM_OFF);

    {   // stage gathered src-node rows + edge attrs (f32), via sort permutation
        const int i = t >> 3, j = t & 7;
        const int pe = perm[eblk + i];             // original edge id
        if (j == 0) row_sh[i] = eidx[pe];          // dest row (non-decreasing over i)
        const int col = eidx[kEdges + pe];
        const float4* src = (const float4*)(nf + (size_t)col * 160);
        for (int c = j; c < 40; c += 8) *(float4*)&nf_sh[i * 164 + c * 4] = src[c];
        const float4* esrc = (const float4*)(ea + (size_t)pe * 32);
        *(float4*)&ea_sh[i * 36 + j * 4] = esrc[j];
    }
    __syncthreads();

    // ---- main K-loop: 24 tiles of K=32, NO barriers. scalar GEMM [32,768]@[768,96],
    //      vector GEMM [96(m,e),768]@[768,32]. per wave: 3 scalar + 3 vector C-tiles.
    f4 accS[3] = {{0.f,0.f,0.f,0.f},{0.f,0.f,0.f,0.f},{0.f,0.f,0.f,0.f}};
    f4 accV[3] = {{0.f,0.f,0.f,0.f},{0.f,0.f,0.f,0.f},{0.f,0.f,0.f,0.f}};
    const int Ms = w >> 1, nb = (w & 1) * 3;       // scalar M-tile, n-tile base
    const int es_ = Ms * 16 + l15;                 // scalar A row (edge)

    // hoist scalar-path edge operands (row es_) into registers: 8 + 24 f32
    const float4 ey0 = *(const float4*)&ea_sh[es_ * 36];
    const float4 ey1 = *(const float4*)&ea_sh[es_ * 36 + 4];
    float eyv[24];
    #pragma unroll
    for (int q = 0; q < 6; ++q)
        *(float4*)&eyv[q * 4] = *(const float4*)&ea_sh[es_ * 36 + 8 + q * 4];

    // phase 1: kt 0..15  (scalar=ss, vector=sv)
    for (int kt = 0; kt < 16; ++kt) {
        const char* wb = msgW + kt * 8192;
        BF aS;                                      // ss: A[j] = xs[u] * ys[j]
        {
            const int uu = kt * 4 + lg;
            const float xs = nf_sh[es_ * 164 + uu];
            aS.u[0] = pk2(xs * ey0.x, xs * ey0.y);
            aS.u[1] = pk2(xs * ey0.z, xs * ey0.w);
            aS.u[2] = pk2(xs * ey1.x, xs * ey1.y);
            aS.u[3] = pk2(xs * ey1.z, xs * ey1.w);
        }
        #pragma unroll
        for (int i = 0; i < 3; ++i)
            accS[i] = mfma16(aS.v, ldB(wb + ((nb + i) * 16 + l15) * 64 + lg * 16), accS[i]);

        BF aV; int prevMv = -1;
        #pragma unroll
        for (int i = 0; i < 3; ++i) {
            const int tv = 3 * w + i, Mv = tv >> 1, Nv = tv & 1;
            if (Mv != prevMv) {
                prevMv = Mv;
                const int m = Mv >> 1, ev = (Mv & 1) * 16 + l15;
                const int kp = kt * 32 + lg * 8;    // sv (k=v*64+u): A[j]=xs[u0+j]*yv[v][m]
                const int vv = kp >> 6, u0 = kp & 63;
                const float ym = ea_sh[ev * 36 + 8 + 3 * vv + m];
                const float4 x0 = *(const float4*)&nf_sh[ev * 164 + u0];
                const float4 x1 = *(const float4*)&nf_sh[ev * 164 + u0 + 4];
                aV.u[0] = pk2(x0.x * ym, x0.y * ym);
                aV.u[1] = pk2(x0.z * ym, x0.w * ym);
                aV.u[2] = pk2(x1.x * ym, x1.y * ym);
                aV.u[3] = pk2(x1.z * ym, x1.w * ym);
            }
            accV[i] = mfma16(aV.v, ldB(wb + (96 + (Nv * 16 + l15)) * 64 + lg * 16), accV[i]);
        }
    }
    // phase 2: kt 16..23  (scalar=vv, vector=vs)
    for (int kt = 16; kt < 24; ++kt) {
        const char* wb = msgW + kt * 8192;
        BF aS;                                      // vv: A[j] = dot(xv[u], yv[j])
        {
            const int uu = (kt - 16) * 4 + lg;
            const float* xp = &nf_sh[es_ * 164 + 64 + 3 * uu];
            const float x0 = xp[0], x1 = xp[1], x2 = xp[2];
            #pragma unroll
            for (int j = 0; j < 4; ++j) {
                float a0 = x0 * eyv[6*j  ] + x1 * eyv[6*j+1] + x2 * eyv[6*j+2];
                float a1 = x0 * eyv[6*j+3] + x1 * eyv[6*j+4] + x2 * eyv[6*j+5];
                aS.u[j] = pk2(a0, a1);
            }
        }
        #pragma unroll
        for (int i = 0; i < 3; ++i)
            accS[i] = mfma16(aS.v, ldB(wb + ((nb + i) * 16 + l15) * 64 + lg * 16), accS[i]);

        BF aV; int prevMv = -1;
        #pragma unroll
        for (int i = 0; i < 3; ++i) {
            const int tv = 3 * w + i, Mv = tv >> 1, Nv = tv & 1;
            if (Mv != prevMv) {
                prevMv = Mv;
                const int m = Mv >> 1, ev = (Mv & 1) * 16 + l15;
                const int uu = (kt - 16) * 4 + lg;  // vs (k=u*8+v): A[j]=xv[u][m]*ys[j]
                const float xm = nf_sh[ev * 164 + 64 + 3 * uu + m];
                const float4 y0 = *(const float4*)&ea_sh[ev * 36];
                const float4 y1 = *(const float4*)&ea_sh[ev * 36 + 4];
                aV.u[0] = pk2(xm * y0.x, xm * y0.y);
                aV.u[1] = pk2(xm * y0.z, xm * y0.w);
                aV.u[2] = pk2(xm * y1.x, xm * y1.y);
                aV.u[3] = pk2(xm * y1.z, xm * y1.w);
            }
            accV[i] = mfma16(aV.v, ldB(wb + (96 + (Nv * 16 + l15)) * 64 + lg * 16), accV[i]);
        }
    }

    __syncthreads();                                // nf_sh/ea_sh dead -> overlay aggloc

    // ---- silu/gates from scalar C (register-sourced); zero aggloc; compute ranks
    #pragma unroll
    for (int i = 0; i < 3; ++i) {
        const int n = (nb + i) * 16 + l15;
        #pragma unroll
        for (int r = 0; r < 4; ++r) {
            const int e = Ms * 16 + lg * 4 + r;
            const float v = accS[i][r];
            if (n < 64) silu_s[e * 72 + n] = f2bf(v * fsig(v));
            else        gat[e * 36 + (n - 64)] = fsig(v);
        }
    }
    for (int idx = t; idx < 32 * 192; idx += 256) aggloc[idx] = 0.f;
    if (t < 32) {                                   // rank = first index with same row
        const int ri = row_sh[t];
        int rk = t;
        for (int j2 = 0; j2 < t; ++j2) if (row_sh[j2] == ri) { rk = j2; break; }
        rank_sh[t] = rk;
    }
    __syncthreads();

    // gate vectors -> pv (bf16)
    #pragma unroll
    for (int i = 0; i < 3; ++i) {
        const int tv = 3 * w + i, Mv = tv >> 1, Nv = tv & 1;
        const int m = Mv >> 1, eb = (Mv & 1) * 16;
        const int u = Nv * 16 + l15;
        #pragma unroll
        for (int r = 0; r < 4; ++r) {
            const int e = eb + lg * 4 + r;
            pv_s[(m * 32 + e) * 40 + u] = f2bf(accV[i][r] * gat[e * 36 + u]);
        }
    }
    __syncthreads();

    // ---- linear (MFMA, B direct from L2) -> LDS aggregation (ds_add_f32)
    {   // ls: [32,64] @ WlsT -> [32,96]
        const char* mls = wout + MLINS_OFF;
        f4 acc[3] = {{0.f,0.f,0.f,0.f},{0.f,0.f,0.f,0.f},{0.f,0.f,0.f,0.f}};
        #pragma unroll
        for (int k0 = 0; k0 < 2; ++k0) {
            const int kg = k0 * 32 + lg * 8;
            bf8 a = *(const bf8*)&silu_s[es_ * 72 + kg];
            #pragma unroll
            for (int i = 0; i < 3; ++i)
                acc[i] = mfma16(a, ldB(mls + ((nb + i) * 16 + l15) * 128 + kg * 2), acc[i]);
        }
        #pragma unroll
        for (int i = 0; i < 3; ++i) {
            const int n = (nb + i) * 16 + l15;
            #pragma unroll
            for (int r = 0; r < 4; ++r) {
                const int e = Ms * 16 + lg * 4 + r;
                atomicAdd(&aggloc[rank_sh[e] * 192 + n], acc[i][r]);
            }
        }
    }
    {   // lv: [96,32] @ WlvT -> [96,32]; rows rr -> (m = rr>>5, e = rr&31)
        const char* mlv = wout + MLINV_OFF;
        f4 acc[3] = {{0.f,0.f,0.f,0.f},{0.f,0.f,0.f,0.f},{0.f,0.f,0.f,0.f}};
        const int kg = lg * 8;
        BF a; int prevMv = -1;
        #pragma unroll
        for (int i = 0; i < 3; ++i) {
            const int tv = 3 * w + i, Mv = tv >> 1, Nv = tv & 1;
            if (Mv != prevMv) { prevMv = Mv; a.v = *(const bf8*)&pv_s[(Mv * 16 + l15) * 40 + kg]; }
            acc[i] = mfma16(a.v, ldB(mlv + (Nv * 16 + l15) * 64 + kg * 2), acc[i]);
        }
        #pragma unroll
        for (int i = 0; i < 3; ++i) {
            const int tv = 3 * w + i, Mv = tv >> 1, Nv = tv & 1;
            const int w2 = Nv * 16 + l15;
            #pragma unroll
            for (int r = 0; r < 4; ++r) {
                const int rr = Mv * 16 + lg * 4 + r;
                const int m = rr >> 5, e = rr & 31;
                atomicAdd(&aggloc[rank_sh[e] * 192 + 96 + w2 * 3 + m], acc[i][r]);
            }
        }
    }
    __syncthreads();

    // ---- flush: one global-atomic pass per DISTINCT row (~4/block), coalesced lanes
    for (int idx = t; idx < 32 * 192; idx += 256) {
        const int ii = idx / 192, c = idx - ii * 192;
        if (rank_sh[ii] == ii)
            atomicAdd(&agg[(size_t)row_sh[ii] * 192 + c], aggloc[idx]);
    }
}

// ================= update kernel: 32 nodes/block, 8 waves, K-split-2, no K-loop barriers ====
__global__ __launch_bounds__(512, 4) void upd_kernel(
    const float* __restrict__ nf, const char* __restrict__ wout,
    float* __restrict__ agg)
{
    __shared__ float nf_sh[32 * 164];    // 20992B
    __shared__ float ag_sh[32 * 196];    // 25088B
    __shared__ float gat[32 * 36];       // 4608B
    __shared__ short silu_s[32 * 72];    // 4608B
    __shared__ short gv_s[96 * 40];      // 7680B
    __shared__ float red[3072];          // 12288B  -> total ~75.3KB => 2 blocks/CU

    const int t = threadIdx.x, w = t >> 6, lane = t & 63;
    const int g = w >> 2, wl = w & 3;              // K-half group, local wave
    const int l15 = lane & 15, lg = lane >> 4;
    const int nblk = blockIdx.x * 32;
    const char* W1 = wout + UPDW1_OFF;
    const char* W2 = wout + UPDW2_OFF;

    {   // stage node rows + agg rows (clamp tail)
        const int i = t >> 4, j = t & 15;
        int n = nblk + i; if (n > kNodes - 1) n = kNodes - 1;
        const float4* src = (const float4*)(nf + (size_t)n * 160);
        for (int c = j; c < 40; c += 16) *(float4*)&nf_sh[i * 164 + c * 4] = src[c];
        const float4* asrc = (const float4*)(agg + (size_t)n * 192);
        for (int c = j; c < 48; c += 16) *(float4*)&ag_sh[i * 196 + c * 4] = asrc[c];
    }
    __syncthreads();

    const int Ms = wl >> 1, nb = (wl & 1) * 3;
    const int es_ = Ms * 16 + l15;

    // ---- scalar K-loop: group g covers tiles [g*112, g*112+112). Region split at kt=192.
    f4 accS[3] = {{0.f,0.f,0.f,0.f},{0.f,0.f,0.f,0.f},{0.f,0.f,0.f,0.f}};
    {
        const int kt0 = g * 112, kt1 = kt0 + 112;
        const int ktSS = kt1 < 192 ? kt1 : 192;
        int kt = kt0;
        for (; kt < ktSS; ++kt) {                    // ss: A[j] = ns[u0+j] * agg_s[v]
            const char* wb = W1 + (size_t)kt * 6144;
            const int kp = kt * 32 + lg * 8;
            const int vv = kp >> 6, u0 = kp & 63;
            const float ys = ag_sh[es_ * 196 + vv];
            const float4 x0 = *(const float4*)&nf_sh[es_ * 164 + u0];
            const float4 x1 = *(const float4*)&nf_sh[es_ * 164 + u0 + 4];
            BF aS;
            aS.u[0] = pk2(x0.x * ys, x0.y * ys);
            aS.u[1] = pk2(x0.z * ys, x0.w * ys);
            aS.u[2] = pk2(x1.x * ys, x1.y * ys);
            aS.u[3] = pk2(x1.z * ys, x1.w * ys);
            #pragma unroll
            for (int i = 0; i < 3; ++i)
                accS[i] = mfma16(aS.v, ldB(wb + ((nb + i) * 16 + l15) * 64 + lg * 16), accS[i]);
        }
        for (; kt < kt1; ++kt) {                     // vv: A[j] = dot(nv[u0+j], agg_v[v])
            const char* wb = W1 + (size_t)kt * 6144;
            const int rp = kt * 32 + lg * 8 - 6144;
            const int vv = rp >> 5, u0 = rp & 31;
            const float* xp = &nf_sh[es_ * 164 + 64 + 3 * u0];
            const float* gp = &ag_sh[es_ * 196 + 96 + 3 * vv];
            const float g0 = gp[0], g1 = gp[1], g2 = gp[2];
            BF aS;
            #pragma unroll
            for (int j = 0; j < 4; ++j) {
                float a0 = xp[6*j  ] * g0 + xp[6*j+1] * g1 + xp[6*j+2] * g2;
                float a1 = xp[6*j+3] * g0 + xp[6*j+4] * g1 + xp[6*j+5] * g2;
                aS.u[j] = pk2(a0, a1);
            }
            #pragma unroll
            for (int i = 0; i < 3; ++i)
                accS[i] = mfma16(aS.v, ldB(wb + ((nb + i) * 16 + l15) * 64 + lg * 16), accS[i]);
        }
    }

    // ---- scalar reduce (group1 -> LDS, group0 adds) + silu/gate epilogue
    if (g == 1) {
        #pragma unroll
        for (int i = 0; i < 3; ++i) {
            const int n = (nb + i) * 16 + l15;
            #pragma unroll
            for (int r = 0; r < 4; ++r)
                red[(Ms * 16 + lg * 4 + r) * 96 + n] = accS[i][r];
        }
    }
    __syncthreads();
    if (g == 0) {
        #pragma unroll
        for (int i = 0; i < 3; ++i) {
            const int n = (nb + i) * 16 + l15;
            #pragma unroll
            for (int r = 0; r < 4; ++r) {
                const int e = Ms * 16 + lg * 4 + r;
                const float v = accS[i][r] + red[e * 96 + n];
                if (n < 64) silu_s[e * 72 + n] = f2bf(v * fsig(v));
                else        gat[e * 36 + (n - 64)] = fsig(v);
            }
        }
    }
    __syncthreads();                                 // redS consumed before redV reuse

    // ---- vector K-loop: group g covers tiles [g*80, g*80+80). Region split at kt=64.
    f4 accV[3] = {{0.f,0.f,0.f,0.f},{0.f,0.f,0.f,0.f},{0.f,0.f,0.f,0.f}};
    {
        const int kt0 = g * 80, kt1 = kt0 + 80;
        const int ktSV = kt1 < 64 ? kt1 : 64;
        int kt = kt0;
        for (; kt < ktSV; ++kt) {                    // sv: A[j] = ns[u0+j] * agg_v[v][m]
            const char* wb = W2 + (size_t)kt * 2048;
            BF aV; int prevMv = -1;
            #pragma unroll
            for (int i = 0; i < 3; ++i) {
                const int tv = 3 * wl + i, Mv = tv >> 1, Nv = tv & 1;
                if (Mv != prevMv) {
                    prevMv = Mv;
                    const int m = Mv >> 1, ev = (Mv & 1) * 16 + l15;
                    const int kp = kt * 32 + lg * 8;
                    const int vv = kp >> 6, u0 = kp & 63;
                    const float ym = ag_sh[ev * 196 + 96 + 3 * vv + m];
                    const float4 x0 = *(const float4*)&nf_sh[ev * 164 + u0];
                    const float4 x1 = *(const float4*)&nf_sh[ev * 164 + u0 + 4];
                    aV.u[0] = pk2(x0.x * ym, x0.y * ym);
                    aV.u[1] = pk2(x0.z * ym, x0.w * ym);
                    aV.u[2] = pk2(x1.x * ym, x1.y * ym);
                    aV.u[3] = pk2(x1.z * ym, x1.w * ym);
                }
                accV[i] = mfma16(aV.v, ldB(wb + (Nv * 16 + l15) * 64 + lg * 16), accV[i]);
            }
        }
        for (; kt < kt1; ++kt) {                     // vs: A[j] = nv[u][m] * agg_s[v0+j]
            const char* wb = W2 + (size_t)kt * 2048;
            BF aV; int prevMv = -1;
            #pragma unroll
            for (int i = 0; i < 3; ++i) {
                const int tv = 3 * wl + i, Mv = tv >> 1, Nv = tv & 1;
                if (Mv != prevMv) {
                    prevMv = Mv;
                    const int m = Mv >> 1, ev = (Mv & 1) * 16 + l15;
                    const int rp = kt * 32 + lg * 8 - 2048;
                    const int u = rp / 96, v0 = rp - u * 96;
                    const float xm = nf_sh[ev * 164 + 64 + 3 * u + m];
                    const float4 y0 = *(const float4*)&ag_sh[ev * 196 + v0];
                    const float4 y1 = *(const float4*)&ag_sh[ev * 196 + v0 + 4];
                    aV.u[0] = pk2(xm * y0.x, xm * y0.y);
                    aV.u[1] = pk2(xm * y0.z, xm * y0.w);
                    aV.u[2] = pk2(xm * y1.x, xm * y1.y);
                    aV.u[3] = pk2(xm * y1.z, xm * y1.w);
                }
                accV[i] = mfma16(aV.v, ldB(wb + (Nv * 16 + l15) * 64 + lg * 16), accV[i]);
            }
        }
    }

    // ---- vector reduce (group1 -> LDS, group0 adds) + gate -> gv
    if (g == 1) {
        #pragma unroll
        for (int i = 0; i < 3; ++i) {
            const int tv = 3 * wl + i, Mv = tv >> 1, Nv = tv & 1;
            #pragma unroll
            for (int r = 0; r < 4; ++r)
                red[(Mv * 16 + lg * 4 + r) * 32 + Nv * 16 + l15] = accV[i][r];
        }
    }
    __syncthreads();
    if (g == 0) {
        #pragma unroll
        for (int i = 0; i < 3; ++i) {
            const int tv = 3 * wl + i, Mv = tv >> 1, Nv = tv & 1;
            const int m = Mv >> 1, eb = (Mv & 1) * 16;
            const int u = Nv * 16 + l15;
            #pragma unroll
            for (int r = 0; r < 4; ++r) {
                const int e = eb + lg * 4 + r;
                const float v = accV[i][r] + red[(Mv * 16 + lg * 4 + r) * 32 + u];
                gv_s[(m * 32 + e) * 40 + u] = f2bf(v * gat[e * 36 + u]);
            }
        }
    }
    __syncthreads();

    // ---- final linears (MFMA, B direct from L2) + residual -> agg cols 0..159; group 0 only
    const int nvalid = kNodes - nblk;
    if (g == 0) {
        {   // ds: [32,64] @ WlsT_u -> [32,64]; 2 N-tiles per wave
            const char* uls = wout + ULINS_OFF;
            f4 acc[2] = {{0.f,0.f,0.f,0.f},{0.f,0.f,0.f,0.f}};
            const int nb2 = (wl & 1) * 2;
            #pragma unroll
            for (int k0 = 0; k0 < 2; ++k0) {
                const int kg = k0 * 32 + lg * 8;
                bf8 a = *(const bf8*)&silu_s[es_ * 72 + kg];
                #pragma unroll
                for (int i = 0; i < 2; ++i)
                    acc[i] = mfma16(a, ldB(uls + ((nb2 + i) * 16 + l15) * 128 + kg * 2), acc[i]);
            }
            #pragma unroll
            for (int i = 0; i < 2; ++i) {
                const int n = (nb2 + i) * 16 + l15;
                #pragma unroll
                for (int r = 0; r < 4; ++r) {
                    const int e = Ms * 16 + lg * 4 + r;
                    if (e < nvalid)
                        agg[(size_t)(nblk + e) * 192 + n] = nf_sh[e * 164 + n] + acc[i][r];
                }
            }
        }
        {   // dv: [96,32] @ WlvT_u -> [96,32]
            const char* ulv = wout + ULINV_OFF;
            f4 acc[3] = {{0.f,0.f,0.f,0.f},{0.f,0.f,0.f,0.f},{0.f,0.f,0.f,0.f}};
            const int kg = lg * 8;
            BF a; int prevMv = -1;
            #pragma unroll
            for (int i = 0; i < 3; ++i) {
                const int tv = 3 * wl + i, Mv = tv >> 1, Nv = tv & 1;
                if (Mv != prevMv) { prevMv = Mv; a.v = *(const bf8*)&gv_s[(Mv * 16 + l15) * 40 + kg]; }
                acc[i] = mfma16(a.v, ldB(ulv + (Nv * 16 + l15) * 64 + kg * 2), acc[i]);
            }
            #pragma unroll
            for (int i = 0; i < 3; ++i) {
                const int tv = 3 * wl + i, Mv = tv >> 1, Nv = tv & 1;
                const int w2 = Nv * 16 + l15;
                #pragma unroll
                for (int r = 0; r < 4; ++r) {
                    const int rr = Mv * 16 + lg * 4 + r;
                    const int m = rr >> 5, e = rr & 31;
                    if (e < nvalid)
                        agg[(size_t)(nblk + e) * 192 + 64 + w2 * 3 + m]
                            = nf_sh[e * 164 + 64 + w2 * 3 + m] + acc[i][r];
                }
            }
        }
    }
}

// ================= final copy: agg rows (cols 0..159) -> d_out [10000][160] ==========
__global__ __launch_bounds__(256) void copy_kernel(const float* __restrict__ agg,
                                                   float* __restrict__ out)
{
    int i = blockIdx.x * 256 + threadIdx.x;       // i indexes [10000][40] float4s
    if (i < 400000) {
        int n = i / 40, c = i - n * 40;
        ((float4*)out)[i] = ((const float4*)agg)[n * 48 + c];
    }
}

extern "C" void kernel_launch(void* const* d_in, const int* in_sizes, int n_in,
                              void* d_out, int out_size, void* d_ws, size_t ws_size,
                              hipStream_t stream) {
    const float* nf   = (const float*)d_in[0];
    const float* ea   = (const float*)d_in[1];
    const int*   eidx = (const int*)d_in[14];
    float* agg = (float*)d_ws;                     // f32 [10000][192] — ONLY ws use
    char*  wout = (char*)d_out;                    // weights + sort scratch until final copy

    hipMemsetAsync(agg, 0, 7680000, stream);
    hipMemsetAsync(wout + CNT_OFF, 0, 40960, stream);
    prep_kernel<<<3760, 256, 0, stream>>>(
        (const float*)d_in[2], (const float*)d_in[3], (const float*)d_in[4],
        (const float*)d_in[5], (const float*)d_in[6], (const float*)d_in[7],
        (const float*)d_in[8], (const float*)d_in[9], (const float*)d_in[10],
        (const float*)d_in[11], (const float*)d_in[12], (const float*)d_in[13], wout);
    hist_kernel<<<391, 256, 0, stream>>>(eidx, (int*)(wout + CNT_OFF));
    scan_kernel<<<1, 256, 0, stream>>>((const int*)(wout + CNT_OFF), (int*)(wout + CUR_OFF));
    scatter_kernel<<<391, 256, 0, stream>>>(eidx, (int*)(wout + CUR_OFF), (int*)(wout + PERM_OFF));
    msg_kernel<<<kEdges / 32, 256, 0, stream>>>(nf, ea, eidx, wout, agg);
    upd_kernel<<<(kNodes + 31) / 32, 512, 0, stream>>>(nf, wout, agg);
    copy_kernel<<<1563, 256, 0, stream>>>(agg, (float*)d_out);
}

// Round 10
// 472.491 us; speedup vs baseline: 1.1109x; 1.1109x over previous
//
#include <hip/hip_runtime.h>
#include <hip/hip_bf16.h>

// irreps: node = 64x0e + 32x1o (160 f32), edge = 8x0e + 8x1o (32 f32)
// hidden = 96x0e + 32x1o ; agg row = 96 scalars + 32*3 vectors = 192 f32
constexpr int kNodes = 10000;
constexpr int kEdges = 100000;

constexpr float INV_SQRT3    = 0.57735026918962576f;
constexpr float INV_SQRT768  = 0.036084391824351615f;  // msg fan
constexpr float INV_SQRT7168 = 0.011811389781538352f;  // upd scalar fan
constexpr float INV_SQRT5120 = 0.013975424859373686f;  // upd vector fan
constexpr float INV_SQRT32   = 0.17677669529663687f;

// d_ws: ONLY the f32 agg accumulator [10000][192] = 7,680,000 B (proven safe size).
// d_out (6.4 MB) holds prepped bf16 weights + edge-sort scratch until the final copy:
constexpr size_t MSGW_OFF  = 0;         // 24 x [128][32] bf16 = 196,608 B
constexpr size_t UPDW1_OFF = 196608;    // 224 x [96][32]      = 1,376,256 B
constexpr size_t UPDW2_OFF = 1572864;   // 160 x [32][32]      = 327,680 B
constexpr size_t MLINS_OFF = 1900544;   // [96][64]            = 12,288 B
constexpr size_t MLINV_OFF = 1912832;   // [32][32]            = 2,048 B
constexpr size_t ULINS_OFF = 1914880;   // [64][64]            = 8,192 B
constexpr size_t ULINV_OFF = 1923072;   // [32][32]            = 2,048 B
constexpr size_t CNT_OFF   = 1926144;   // 10000 int (per-node edge count)
constexpr size_t CUR_OFF   = 1967104;   // 10000 int (scatter cursors)
constexpr size_t PERM_OFF  = 2008064;   // 100000 int (dest-sorted edge ids), end 2,408,064 < 6.4MB

typedef __attribute__((ext_vector_type(8))) short bf8;  // 8 bf16 (4 VGPR) MFMA operand
typedef __attribute__((ext_vector_type(4))) float f4;   // MFMA accumulator
union BF { bf8 v; short s[8]; unsigned u[4]; };

__device__ __forceinline__ short f2bf(float f) {   // RNE f32->bf16 (cold paths)
    union { float f; unsigned u; } c; c.f = f;
    unsigned r = c.u + 0x7fffu + ((c.u >> 16) & 1u);
    return (short)(r >> 16);
}
__device__ __forceinline__ unsigned pk2(float lo, float hi) {  // v_cvt_pk_bf16_f32
    union { __hip_bfloat162 h; unsigned u; } c;
    c.h = __float22bfloat162_rn(make_float2(lo, hi));
    return c.u;
}
__device__ __forceinline__ float bf2f(unsigned short s) {
    union { float f; unsigned u; } c; c.u = ((unsigned)s) << 16; return c.f;
}
__device__ __forceinline__ f4 mfma16(bf8 a, bf8 b, f4 c) {
    return __builtin_amdgcn_mfma_f32_16x16x32_bf16(a, b, c, 0, 0, 0);
}
__device__ __forceinline__ bf8 ldB(const char* p) {  // direct L2-served B-fragment
    return *(const bf8*)p;
}
__device__ __forceinline__ float fsig(float x) { return 1.0f / (1.0f + __expf(-x)); }

// ================= prep: scale + transpose + reorder weights to bf16 (into d_out) ==========
__global__ void prep_kernel(
    const float* __restrict__ Wmss, const float* __restrict__ Wmvv,
    const float* __restrict__ Wmsv, const float* __restrict__ Wmvs,
    const float* __restrict__ Wlms, const float* __restrict__ Wlmv,
    const float* __restrict__ Wuss, const float* __restrict__ Wuvv,
    const float* __restrict__ Wusv, const float* __restrict__ Wuvs,
    const float* __restrict__ Wlus, const float* __restrict__ Wluv,
    char* __restrict__ wout)
{
    int i = blockIdx.x * 256 + threadIdx.x;
    float v;
    short* dst;
    if (i < 98304) {                        // msgW: [24][128][32]
        dst = (short*)(wout + MSGW_OFF) + i;
        int t = i >> 12, q = i & 4095, r = q >> 5, c = q & 31;
        int k = t * 32 + c;
        if (r < 96) {                       // W1: k<512 ss (k=u*8+v); else vv natural
            v = (k < 512 ? Wmss[k * 96 + r]
                         : Wmvv[(k - 512) * 96 + r] * INV_SQRT3) * INV_SQRT768;
        } else {                            // W2: k<512 sv REORDERED k=v*64+u; else vs natural
            int n2 = r - 96;
            if (k < 512) { int u = k & 63, vv = k >> 6; v = Wmsv[(u * 8 + vv) * 32 + n2] * INV_SQRT768; }
            else         { v = Wmvs[(k - 512) * 32 + n2] * INV_SQRT768; }
        }
    } else if (i < 786432) {                // updW1: [224][96][32]
        int j = i - 98304;
        dst = (short*)(wout + UPDW1_OFF) + j;
        int t = j / 3072, q = j % 3072, r = q >> 5, c = q & 31;
        int k = t * 32 + c;
        if (k < 6144) { int u = k & 63, vv = k >> 6;              // ss REORDERED k=v*64+u
            v = Wuss[(u * 96 + vv) * 96 + r] * INV_SQRT7168; }
        else { int r2 = k - 6144; int u = r2 & 31, vv = r2 >> 5;  // vv REORDERED k=v*32+u
            v = Wuvv[(u * 32 + vv) * 96 + r] * (INV_SQRT3 * INV_SQRT7168); }
    } else if (i < 950272) {                // updW2: [160][32][32]
        int j = i - 786432;
        dst = (short*)(wout + UPDW2_OFF) + j;
        int t = j >> 10, q = j & 1023, r = q >> 5, c = q & 31;
        int k = t * 32 + c;
        if (k < 2048) { int u = k & 63, vv = k >> 6;              // sv REORDERED k=v*64+u
            v = Wusv[(u * 32 + vv) * 32 + r] * INV_SQRT5120; }
        else { int r2 = k - 2048;                                  // vs natural u*96+v
            v = Wuvs[r2 * 32 + r] * INV_SQRT5120; }
    } else if (i < 956416) {                // mlin_s: [96][64]
        int j = i - 950272;
        dst = (short*)(wout + MLINS_OFF) + j;
        int n = j >> 6, kk = j & 63;
        v = Wlms[kk * 96 + n] * 0.125f;
    } else if (i < 957440) {                // mlin_v: [32][32]
        int j = i - 956416;
        dst = (short*)(wout + MLINV_OFF) + j;
        int n = j >> 5, kk = j & 31;
        v = Wlmv[kk * 32 + n] * INV_SQRT32;
    } else if (i < 961536) {                // ulin_s: [64][64]
        int j = i - 957440;
        dst = (short*)(wout + ULINS_OFF) + j;
        int n = j >> 6, kk = j & 63;
        v = Wlus[kk * 64 + n] * 0.125f;
    } else if (i < 962560) {                // ulin_v: [32][32]
        int j = i - 961536;
        dst = (short*)(wout + ULINV_OFF) + j;
        int n = j >> 5, kk = j & 31;
        v = Wluv[kk * 32 + n] * INV_SQRT32;
    } else return;
    *dst = f2bf(v);
}

// ================= edge sort by destination row: histogram -> scan -> scatter =========
__global__ __launch_bounds__(256) void hist_kernel(const int* __restrict__ eidx,
                                                   int* __restrict__ cnt)
{
    int e = blockIdx.x * 256 + threadIdx.x;
    if (e < kEdges) atomicAdd(&cnt[eidx[e]], 1);
}

__global__ __launch_bounds__(256) void scan_kernel(const int* __restrict__ cnt,
                                                   int* __restrict__ cursor)
{   // single block: exclusive prefix over 10000 counts -> scatter cursors
    __shared__ int psum[256];
    const int t = threadIdx.x, base = t * 40;      // 256*40 = 10240 >= 10000
    int s = 0;
    for (int j = 0; j < 40; ++j) { int idx = base + j; if (idx < kNodes) s += cnt[idx]; }
    psum[t] = s;
    __syncthreads();
    if (t == 0) { int a = 0; for (int i = 0; i < 256; ++i) { int x = psum[i]; psum[i] = a; a += x; } }
    __syncthreads();
    int run = psum[t];
    for (int j = 0; j < 40; ++j) {
        int idx = base + j;
        if (idx < kNodes) { cursor[idx] = run; run += cnt[idx]; }
    }
}

__global__ __launch_bounds__(256) void scatter_kernel(const int* __restrict__ eidx,
                                                      int* __restrict__ cursor,
                                                      int* __restrict__ perm)
{
    int e = blockIdx.x * 256 + threadIdx.x;
    if (e < kEdges) {
        int p = atomicAdd(&cursor[eidx[e]], 1);
        perm[p] = e;
    }
}

// ================= message kernel: 64 DEST-SORTED edges/block, 4 waves ================
// kt-outer / M-subtile-inner: per kt the 6 B-fragments are loaded ONCE into registers
// and applied to 2 M-subtiles of 32 edges — halves B-load latency exposures per edge
// and covers them with real work. nf staged bf16 (LDS 49.8KB -> 3 blocks/CU).
// Scatter: compact rank-indexed LDS accumulator (ds_add) + per-distinct-row flush.
__global__ __launch_bounds__(256, 3) void msg_kernel(
    const float* __restrict__ nf, const float* __restrict__ ea,
    const int* __restrict__ eidx, const char* __restrict__ wout,
    float* __restrict__ agg)
{
    __shared__ char pool[49792];
    unsigned short* nf_bf = (unsigned short*)pool;   // [64][168] bf16  21504B (K-phase)
    float* ea_sh  = (float*)(pool + 21504);          // [64][36] f32    9216B  (K-phase)
    // epilogue overlay on [0, 30720):
    short* silu_s = (short*)pool;                    // [64][72] bf16   9216B
    short* gat    = (short*)(pool + 9216);           // [64][40] bf16   5120B
    short* pv_s   = (short*)(pool + 14336);          // [192][40] bf16  15360B (end 29696)
    float* aggloc = (float*)(pool + 30720);          // [24][192] f32   18432B
    int*   row_sh = (int*)(pool + 49152);            // [64]
    int*   rank_sh= (int*)(pool + 49408);            // [64] rank index or -1
    int*   rrow   = (int*)(pool + 49664);            // [24] distinct rows
    int*   nh_sh  = (int*)(pool + 49760);            // [1]

    const int t = threadIdx.x, w = t >> 6, lane = t & 63;
    const int l15 = lane & 15, lg = lane >> 4;       // lg in [0,4): k-group
    const int eblk = blockIdx.x * 64;

    const char* msgW = wout + MSGW_OFF;
    const int*  perm = (const int*)(wout + PERM_OFF);

    {   // stage: 4 threads per edge; nf converted f32->bf16 on the fly; invalid -> ea=0
        const int i = t >> 2, j = t & 3;
        const bool valid = (eblk + i) < kEdges;
        const int pe = perm[valid ? eblk + i : kEdges - 1];
        if (j == 0) row_sh[i] = eidx[pe];
        const int col = eidx[kEdges + pe];
        const float4* src = (const float4*)(nf + (size_t)col * 160);
        for (int c = j; c < 40; c += 4) {
            float4 v4 = src[c];
            *(uint2*)&nf_bf[i * 168 + c * 4] = make_uint2(pk2(v4.x, v4.y), pk2(v4.z, v4.w));
        }
        const float4* esrc = (const float4*)(ea + (size_t)pe * 32);
        const float4 z4 = make_float4(0.f, 0.f, 0.f, 0.f);
        *(float4*)&ea_sh[i * 36 + j * 8]     = valid ? esrc[j * 2]     : z4;
        *(float4*)&ea_sh[i * 36 + j * 8 + 4] = valid ? esrc[j * 2 + 1] : z4;
    }
    __syncthreads();

    // ---- K-loop: kt outer, m-subtile inner. Per wave: scalar tile (Ms, nb), 3 N-tiles;
    //      vector tiles tv=3w+i per subtile. acc[2][3] each.
    f4 accS[2][3] = {}; f4 accV[2][3] = {};
    const int Ms = w >> 1, nb = (w & 1) * 3;
    float4 ey0[2], ey1[2];                           // edge scalars of own scalar-row, per m
    #pragma unroll
    for (int m = 0; m < 2; ++m) {
        const int es = m * 32 + Ms * 16 + l15;
        ey0[m] = *(const float4*)&ea_sh[es * 36];
        ey1[m] = *(const float4*)&ea_sh[es * 36 + 4];
    }

    // phase 1: kt 0..15 (scalar=ss, vector=sv)
    for (int kt = 0; kt < 16; ++kt) {
        const char* wb = msgW + kt * 8192;
        bf8 bs[3], bv[3];
        #pragma unroll
        for (int i = 0; i < 3; ++i) {
            bs[i] = ldB(wb + ((nb + i) * 16 + l15) * 64 + lg * 16);
            bv[i] = ldB(wb + (96 + (((3 * w + i) & 1) * 16 + l15)) * 64 + lg * 16);
        }
        #pragma unroll
        for (int m = 0; m < 2; ++m) {
            const int es = m * 32 + Ms * 16 + l15;
            const int uu = kt * 4 + lg;
            const float xs = bf2f(nf_bf[es * 168 + uu]);   // ss: A[j] = xs[u]*ys[j]
            BF aS;
            aS.u[0] = pk2(xs * ey0[m].x, xs * ey0[m].y);
            aS.u[1] = pk2(xs * ey0[m].z, xs * ey0[m].w);
            aS.u[2] = pk2(xs * ey1[m].x, xs * ey1[m].y);
            aS.u[3] = pk2(xs * ey1[m].z, xs * ey1[m].w);
            #pragma unroll
            for (int i = 0; i < 3; ++i) accS[m][i] = mfma16(aS.v, bs[i], accS[m][i]);

            BF aV; int prevMv = -1;
            #pragma unroll
            for (int i = 0; i < 3; ++i) {
                const int tv = 3 * w + i, Mv = tv >> 1;
                if (Mv != prevMv) {
                    prevMv = Mv;
                    const int mc = Mv >> 1, ev = m * 32 + (Mv & 1) * 16 + l15;
                    const int kp = kt * 32 + lg * 8;       // sv (k=v*64+u): A[j]=xs[u0+j]*yv[v][mc]
                    const int vv = kp >> 6, u0 = kp & 63;
                    const float ym = ea_sh[ev * 36 + 8 + 3 * vv + mc];
                    const uint4 xq = *(const uint4*)&nf_bf[ev * 168 + u0];
                    aV.u[0] = pk2(__uint_as_float(xq.x << 16) * ym, __uint_as_float(xq.x & 0xffff0000u) * ym);
                    aV.u[1] = pk2(__uint_as_float(xq.y << 16) * ym, __uint_as_float(xq.y & 0xffff0000u) * ym);
                    aV.u[2] = pk2(__uint_as_float(xq.z << 16) * ym, __uint_as_float(xq.z & 0xffff0000u) * ym);
                    aV.u[3] = pk2(__uint_as_float(xq.w << 16) * ym, __uint_as_float(xq.w & 0xffff0000u) * ym);
                }
                accV[m][i] = mfma16(aV.v, bv[i], accV[m][i]);
            }
        }
    }
    // phase 2: kt 16..23 (scalar=vv, vector=vs)
    for (int kt = 16; kt < 24; ++kt) {
        const char* wb = msgW + kt * 8192;
        bf8 bs[3], bv[3];
        #pragma unroll
        for (int i = 0; i < 3; ++i) {
            bs[i] = ldB(wb + ((nb + i) * 16 + l15) * 64 + lg * 16);
            bv[i] = ldB(wb + (96 + (((3 * w + i) & 1) * 16 + l15)) * 64 + lg * 16);
        }
        const int uu = (kt - 16) * 4 + lg;
        #pragma unroll
        for (int m = 0; m < 2; ++m) {
            const int es = m * 32 + Ms * 16 + l15;
            // vv: A[j] = dot(xv[u], yv[j]) (w3j folded into W)
            const float x0 = bf2f(nf_bf[es * 168 + 64 + 3 * uu]);
            const float x1 = bf2f(nf_bf[es * 168 + 64 + 3 * uu + 1]);
            const float x2 = bf2f(nf_bf[es * 168 + 64 + 3 * uu + 2]);
            float ey_[24];
            #pragma unroll
            for (int q = 0; q < 6; ++q)
                *(float4*)&ey_[q * 4] = *(const float4*)&ea_sh[es * 36 + 8 + q * 4];
            BF aS;
            #pragma unroll
            for (int j = 0; j < 4; ++j) {
                float a0 = x0 * ey_[6*j  ] + x1 * ey_[6*j+1] + x2 * ey_[6*j+2];
                float a1 = x0 * ey_[6*j+3] + x1 * ey_[6*j+4] + x2 * ey_[6*j+5];
                aS.u[j] = pk2(a0, a1);
            }
            #pragma unroll
            for (int i = 0; i < 3; ++i) accS[m][i] = mfma16(aS.v, bs[i], accS[m][i]);

            BF aV; int prevMv = -1;
            #pragma unroll
            for (int i = 0; i < 3; ++i) {
                const int tv = 3 * w + i, Mv = tv >> 1;
                if (Mv != prevMv) {
                    prevMv = Mv;
                    const int mc = Mv >> 1, ev = m * 32 + (Mv & 1) * 16 + l15;
                    const float xm = bf2f(nf_bf[ev * 168 + 64 + 3 * uu + mc]);  // vs: A[j]=xv[u][mc]*ys[j]
                    const float4 y0 = *(const float4*)&ea_sh[ev * 36];
                    const float4 y1 = *(const float4*)&ea_sh[ev * 36 + 4];
                    aV.u[0] = pk2(xm * y0.x, xm * y0.y);
                    aV.u[1] = pk2(xm * y0.z, xm * y0.w);
                    aV.u[2] = pk2(xm * y1.x, xm * y1.y);
                    aV.u[3] = pk2(xm * y1.z, xm * y1.w);
                }
                accV[m][i] = mfma16(aV.v, bv[i], accV[m][i]);
            }
        }
    }

    __syncthreads();                                 // nf/ea dead -> overlay epilogue bufs

    // ---- silu/gates from scalar C; rank compression (t==0); zero aggloc
    #pragma unroll
    for (int m = 0; m < 2; ++m)
        #pragma unroll
        for (int i = 0; i < 3; ++i) {
            const int n = (nb + i) * 16 + l15;
            #pragma unroll
            for (int r = 0; r < 4; ++r) {
                const int em = m * 32 + Ms * 16 + lg * 4 + r;
                const float v = accS[m][i][r];
                if (n < 64) silu_s[em * 72 + n] = f2bf(v * fsig(v));
                else        gat[em * 40 + (n - 64)] = f2bf(fsig(v));
            }
        }
    for (int idx = t; idx < 24 * 192; idx += 256) aggloc[idx] = 0.f;
    if (t == 0) {                                    // runs are contiguous (sorted rows)
        int nh = 0, prev = -1, cur = -1;
        for (int i2 = 0; i2 < 64; ++i2) {
            const int r = row_sh[i2];
            if (r != prev) { cur = (nh < 24) ? nh : -1; if (cur >= 0) rrow[cur] = r; ++nh; prev = r; }
            rank_sh[i2] = cur;
        }
        nh_sh[0] = (nh < 24) ? nh : 24;
    }
    __syncthreads();

    // ---- gate vectors -> pv (bf16), rows rr = mc*64 + em
    #pragma unroll
    for (int m = 0; m < 2; ++m)
        #pragma unroll
        for (int i = 0; i < 3; ++i) {
            const int tv = 3 * w + i, Mv = tv >> 1, Nv = tv & 1;
            const int mc = Mv >> 1, eb = (Mv & 1) * 16;
            const int u = Nv * 16 + l15;
            #pragma unroll
            for (int r = 0; r < 4; ++r) {
                const int em = m * 32 + eb + lg * 4 + r;
                pv_s[(mc * 64 + em) * 40 + u] = f2bf(accV[m][i][r] * bf2f(gat[em * 40 + u]));
            }
        }
    __syncthreads();

    // ---- linear (MFMA, B direct from L2) -> rank-indexed LDS accumulation (ds_add)
    {   // ls: [64,64] @ WlsT -> [64,96]; 4M x 6N tiles, 6 per wave
        const char* mls = wout + MLINS_OFF;
        f4 acc[6] = {};
        #pragma unroll
        for (int k0 = 0; k0 < 2; ++k0) {
            const int kg = k0 * 32 + lg * 8;
            #pragma unroll
            for (int i2 = 0; i2 < 6; ++i2) {
                const int tt = w * 6 + i2, Ms2 = tt & 3, Nn = tt >> 2;
                bf8 a = *(const bf8*)&silu_s[(Ms2 * 16 + l15) * 72 + kg];
                acc[i2] = mfma16(a, ldB(mls + (Nn * 16 + l15) * 128 + kg * 2), acc[i2]);
            }
        }
        #pragma unroll
        for (int i2 = 0; i2 < 6; ++i2) {
            const int tt = w * 6 + i2, Ms2 = tt & 3, Nn = tt >> 2;
            const int n = Nn * 16 + l15;
            #pragma unroll
            for (int r = 0; r < 4; ++r) {
                const int e64 = Ms2 * 16 + lg * 4 + r;
                const int ri = rank_sh[e64];
                if (ri >= 0) atomicAdd(&aggloc[ri * 192 + n], acc[i2][r]);
                else         atomicAdd(&agg[(size_t)row_sh[e64] * 192 + n], acc[i2][r]);
            }
        }
    }
    {   // lv: [192,32] @ WlvT -> [192,32]; 12M x 2N tiles, 6 per wave (pairs share A)
        const char* mlv = wout + MLINV_OFF;
        f4 acc[6] = {};
        const int kg = lg * 8;
        BF a; int prevMv = -1;
        #pragma unroll
        for (int i2 = 0; i2 < 6; ++i2) {
            const int tt = w * 6 + i2, Mv2 = tt >> 1, Nv2 = tt & 1;
            if (Mv2 != prevMv) { prevMv = Mv2; a.v = *(const bf8*)&pv_s[(Mv2 * 16 + l15) * 40 + kg]; }
            acc[i2] = mfma16(a.v, ldB(mlv + (Nv2 * 16 + l15) * 64 + kg * 2), acc[i2]);
        }
        #pragma unroll
        for (int i2 = 0; i2 < 6; ++i2) {
            const int tt = w * 6 + i2, Mv2 = tt >> 1, Nv2 = tt & 1;
            const int w2 = Nv2 * 16 + l15;
            #pragma unroll
            for (int r = 0; r < 4; ++r) {
                const int rr = Mv2 * 16 + lg * 4 + r;
                const int mc = rr >> 6, e64 = rr & 63;
                const int c = 96 + w2 * 3 + mc;
                const int ri = rank_sh[e64];
                if (ri >= 0) atomicAdd(&aggloc[ri * 192 + c], acc[i2][r]);
                else         atomicAdd(&agg[(size_t)row_sh[e64] * 192 + c], acc[i2][r]);
            }
        }
    }
    __syncthreads();

    // ---- flush: one coalesced global-atomic pass per distinct destination row
    const int nh = nh_sh[0];
    for (int idx = t; idx < nh * 192; idx += 256) {
        const int h = idx / 192, c = idx - h * 192;
        atomicAdd(&agg[(size_t)rrow[h] * 192 + c], aggloc[h * 192 + c]);
    }
}

// ================= update kernel: 32 nodes/block, 8 waves, K-split-2, no K-loop barriers ====
__global__ __launch_bounds__(512, 4) void upd_kernel(
    const float* __restrict__ nf, const char* __restrict__ wout,
    float* __restrict__ agg)
{
    __shared__ float nf_sh[32 * 164];    // 20992B
    __shared__ float ag_sh[32 * 196];    // 25088B
    __shared__ float gat[32 * 36];       // 4608B
    __shared__ short silu_s[32 * 72];    // 4608B
    __shared__ short gv_s[96 * 40];      // 7680B
    __shared__ float red[3072];          // 12288B  -> total ~75.3KB => 2 blocks/CU

    const int t = threadIdx.x, w = t >> 6, lane = t & 63;
    const int g = w >> 2, wl = w & 3;              // K-half group, local wave
    const int l15 = lane & 15, lg = lane >> 4;
    const int nblk = blockIdx.x * 32;
    const char* W1 = wout + UPDW1_OFF;
    const char* W2 = wout + UPDW2_OFF;

    {   // stage node rows + agg rows (clamp tail)
        const int i = t >> 4, j = t & 15;
        int n = nblk + i; if (n > kNodes - 1) n = kNodes - 1;
        const float4* src = (const float4*)(nf + (size_t)n * 160);
        for (int c = j; c < 40; c += 16) *(float4*)&nf_sh[i * 164 + c * 4] = src[c];
        const float4* asrc = (const float4*)(agg + (size_t)n * 192);
        for (int c = j; c < 48; c += 16) *(float4*)&ag_sh[i * 196 + c * 4] = asrc[c];
    }
    __syncthreads();

    const int Ms = wl >> 1, nb = (wl & 1) * 3;
    const int es_ = Ms * 16 + l15;

    // ---- scalar K-loop: group g covers tiles [g*112, g*112+112). Region split at kt=192.
    f4 accS[3] = {{0.f,0.f,0.f,0.f},{0.f,0.f,0.f,0.f},{0.f,0.f,0.f,0.f}};
    {
        const int kt0 = g * 112, kt1 = kt0 + 112;
        const int ktSS = kt1 < 192 ? kt1 : 192;
        int kt = kt0;
        for (; kt < ktSS; ++kt) {                    // ss: A[j] = ns[u0+j] * agg_s[v]
            const char* wb = W1 + (size_t)kt * 6144;
            const int kp = kt * 32 + lg * 8;
            const int vv = kp >> 6, u0 = kp & 63;
            const float ys = ag_sh[es_ * 196 + vv];
            const float4 x0 = *(const float4*)&nf_sh[es_ * 164 + u0];
            const float4 x1 = *(const float4*)&nf_sh[es_ * 164 + u0 + 4];
            BF aS;
            aS.u[0] = pk2(x0.x * ys, x0.y * ys);
            aS.u[1] = pk2(x0.z * ys, x0.w * ys);
            aS.u[2] = pk2(x1.x * ys, x1.y * ys);
            aS.u[3] = pk2(x1.z * ys, x1.w * ys);
            #pragma unroll
            for (int i = 0; i < 3; ++i)
                accS[i] = mfma16(aS.v, ldB(wb + ((nb + i) * 16 + l15) * 64 + lg * 16), accS[i]);
        }
        for (; kt < kt1; ++kt) {                     // vv: A[j] = dot(nv[u0+j], agg_v[v])
            const char* wb = W1 + (size_t)kt * 6144;
            const int rp = kt * 32 + lg * 8 - 6144;
            const int vv = rp >> 5, u0 = rp & 31;
            const float* xp = &nf_sh[es_ * 164 + 64 + 3 * u0];
            const float* gp = &ag_sh[es_ * 196 + 96 + 3 * vv];
            const float g0 = gp[0], g1 = gp[1], g2 = gp[2];
            BF aS;
            #pragma unroll
            for (int j = 0; j < 4; ++j) {
                float a0 = xp[6*j  ] * g0 + xp[6*j+1] * g1 + xp[6*j+2] * g2;
                float a1 = xp[6*j+3] * g0 + xp[6*j+4] * g1 + xp[6*j+5] * g2;
                aS.u[j] = pk2(a0, a1);
            }
            #pragma unroll
            for (int i = 0; i < 3; ++i)
                accS[i] = mfma16(aS.v, ldB(wb + ((nb + i) * 16 + l15) * 64 + lg * 16), accS[i]);
        }
    }

    // ---- scalar reduce (group1 -> LDS, group0 adds) + silu/gate epilogue
    if (g == 1) {
        #pragma unroll
        for (int i = 0; i < 3; ++i) {
            const int n = (nb + i) * 16 + l15;
            #pragma unroll
            for (int r = 0; r < 4; ++r)
                red[(Ms * 16 + lg * 4 + r) * 96 + n] = accS[i][r];
        }
    }
    __syncthreads();
    if (g == 0) {
        #pragma unroll
        for (int i = 0; i < 3; ++i) {
            const int n = (nb + i) * 16 + l15;
            #pragma unroll
            for (int r = 0; r < 4; ++r) {
                const int e = Ms * 16 + lg * 4 + r;
                const float v = accS[i][r] + red[e * 96 + n];
                if (n < 64) silu_s[e * 72 + n] = f2bf(v * fsig(v));
                else        gat[e * 36 + (n - 64)] = fsig(v);
            }
        }
    }
    __syncthreads();                                 // redS consumed before redV reuse

    // ---- vector K-loop: group g covers tiles [g*80, g*80+80). Region split at kt=64.
    f4 accV[3] = {{0.f,0.f,0.f,0.f},{0.f,0.f,0.f,0.f},{0.f,0.f,0.f,0.f}};
    {
        const int kt0 = g * 80, kt1 = kt0 + 80;
        const int ktSV = kt1 < 64 ? kt1 : 64;
        int kt = kt0;
        for (; kt < ktSV; ++kt) {                    // sv: A[j] = ns[u0+j] * agg_v[v][m]
            const char* wb = W2 + (size_t)kt * 2048;
            BF aV; int prevMv = -1;
            #pragma unroll
            for (int i = 0; i < 3; ++i) {
                const int tv = 3 * wl + i, Mv = tv >> 1, Nv = tv & 1;
                if (Mv != prevMv) {
                    prevMv = Mv;
                    const int m = Mv >> 1, ev = (Mv & 1) * 16 + l15;
                    const int kp = kt * 32 + lg * 8;
                    const int vv = kp >> 6, u0 = kp & 63;
                    const float ym = ag_sh[ev * 196 + 96 + 3 * vv + m];
                    const float4 x0 = *(const float4*)&nf_sh[ev * 164 + u0];
                    const float4 x1 = *(const float4*)&nf_sh[ev * 164 + u0 + 4];
                    aV.u[0] = pk2(x0.x * ym, x0.y * ym);
                    aV.u[1] = pk2(x0.z * ym, x0.w * ym);
                    aV.u[2] = pk2(x1.x * ym, x1.y * ym);
                    aV.u[3] = pk2(x1.z * ym, x1.w * ym);
                }
                accV[i] = mfma16(aV.v, ldB(wb + (Nv * 16 + l15) * 64 + lg * 16), accV[i]);
            }
        }
        for (; kt < kt1; ++kt) {                     // vs: A[j] = nv[u][m] * agg_s[v0+j]
            const char* wb = W2 + (size_t)kt * 2048;
            BF aV; int prevMv = -1;
            #pragma unroll
            for (int i = 0; i < 3; ++i) {
                const int tv = 3 * wl + i, Mv = tv >> 1, Nv = tv & 1;
                if (Mv != prevMv) {
                    prevMv = Mv;
                    const int m = Mv >> 1, ev = (Mv & 1) * 16 + l15;
                    const int rp = kt * 32 + lg * 8 - 2048;
                    const int u = rp / 96, v0 = rp - u * 96;
                    const float xm = nf_sh[ev * 164 + 64 + 3 * u + m];
                    const float4 y0 = *(const float4*)&ag_sh[ev * 196 + v0];
                    const float4 y1 = *(const float4*)&ag_sh[ev * 196 + v0 + 4];
                    aV.u[0] = pk2(xm * y0.x, xm * y0.y);
                    aV.u[1] = pk2(xm * y0.z, xm * y0.w);
                    aV.u[2] = pk2(xm * y1.x, xm * y1.y);
                    aV.u[3] = pk2(xm * y1.z, xm * y1.w);
                }
                accV[i] = mfma16(aV.v, ldB(wb + (Nv * 16 + l15) * 64 + lg * 16), accV[i]);
            }
        }
    }

    // ---- vector reduce (group1 -> LDS, group0 adds) + gate -> gv
    if (g == 1) {
        #pragma unroll
        for (int i = 0; i < 3; ++i) {
            const int tv = 3 * wl + i, Mv = tv >> 1, Nv = tv & 1;
            #pragma unroll
            for (int r = 0; r < 4; ++r)
                red[(Mv * 16 + lg * 4 + r) * 32 + Nv * 16 + l15] = accV[i][r];
        }
    }
    __syncthreads();
    if (g == 0) {
        #pragma unroll
        for (int i = 0; i < 3; ++i) {
            const int tv = 3 * wl + i, Mv = tv >> 1, Nv = tv & 1;
            const int m = Mv >> 1, eb = (Mv & 1) * 16;
            const int u = Nv * 16 + l15;
            #pragma unroll
            for (int r = 0; r < 4; ++r) {
                const int e = eb + lg * 4 + r;
                const float v = accV[i][r] + red[(Mv * 16 + lg * 4 + r) * 32 + u];
                gv_s[(m * 32 + e) * 40 + u] = f2bf(v * gat[e * 36 + u]);
            }
        }
    }
    __syncthreads();

    // ---- final linears (MFMA, B direct from L2) + residual -> agg cols 0..159; group 0 only
    const int nvalid = kNodes - nblk;
    if (g == 0) {
        {   // ds: [32,64] @ WlsT_u -> [32,64]; 2 N-tiles per wave
            const char* uls = wout + ULINS_OFF;
            f4 acc[2] = {{0.f,0.f,0.f,0.f},{0.f,0.f,0.f,0.f}};
            const int nb2 = (wl & 1) * 2;
            #pragma unroll
            for (int k0 = 0; k0 < 2; ++k0) {
                const int kg = k0 * 32 + lg * 8;
                bf8 a = *(const bf8*)&silu_s[es_ * 72 + kg];
                #pragma unroll
                for (int i = 0; i < 2; ++i)
                    acc[i] = mfma16(a, ldB(uls + ((nb2 + i) * 16 + l15) * 128 + kg * 2), acc[i]);
            }
            #pragma unroll
            for (int i = 0; i < 2; ++i) {
                const int n = (nb2 + i) * 16 + l15;
                #pragma unroll
                for (int r = 0; r < 4; ++r) {
                    const int e = Ms * 16 + lg * 4 + r;
                    if (e < nvalid)
                        agg[(size_t)(nblk + e) * 192 + n] = nf_sh[e * 164 + n] + acc[i][r];
                }
            }
        }
        {   // dv: [96,32] @ WlvT_u -> [96,32]
            const char* ulv = wout + ULINV_OFF;
            f4 acc[3] = {{0.f,0.f,0.f,0.f},{0.f,0.f,0.f,0.f},{0.f,0.f,0.f,0.f}};
            const int kg = lg * 8;
            BF a; int prevMv = -1;
            #pragma unroll
            for (int i = 0; i < 3; ++i) {
                const int tv = 3 * wl + i, Mv = tv >> 1, Nv = tv & 1;
                if (Mv != prevMv) { prevMv = Mv; a.v = *(const bf8*)&gv_s[(Mv * 16 + l15) * 40 + kg]; }
                acc[i] = mfma16(a.v, ldB(ulv + (Nv * 16 + l15) * 64 + kg * 2), acc[i]);
            }
            #pragma unroll
            for (int i = 0; i < 3; ++i) {
                const int tv = 3 * wl + i, Mv = tv >> 1, Nv = tv & 1;
                const int w2 = Nv * 16 + l15;
                #pragma unroll
                for (int r = 0; r < 4; ++r) {
                    const int rr = Mv * 16 + lg * 4 + r;
                    const int m = rr >> 5, e = rr & 31;
                    if (e < nvalid)
                        agg[(size_t)(nblk + e) * 192 + 64 + w2 * 3 + m]
                            = nf_sh[e * 164 + 64 + w2 * 3 + m] + acc[i][r];
                }
            }
        }
    }
}

// ================= final copy: agg rows (cols 0..159) -> d_out [10000][160] ==========
__global__ __launch_bounds__(256) void copy_kernel(const float* __restrict__ agg,
                                                   float* __restrict__ out)
{
    int i = blockIdx.x * 256 + threadIdx.x;       // i indexes [10000][40] float4s
    if (i < 400000) {
        int n = i / 40, c = i - n * 40;
        ((float4*)out)[i] = ((const float4*)agg)[n * 48 + c];
    }
}

extern "C" void kernel_launch(void* const* d_in, const int* in_sizes, int n_in,
                              void* d_out, int out_size, void* d_ws, size_t ws_size,
                              hipStream_t stream) {
    const float* nf   = (const float*)d_in[0];
    const float* ea   = (const float*)d_in[1];
    const int*   eidx = (const int*)d_in[14];
    float* agg = (float*)d_ws;                     // f32 [10000][192] — ONLY ws use
    char*  wout = (char*)d_out;                    // weights + sort scratch until final copy

    hipMemsetAsync(agg, 0, 7680000, stream);
    hipMemsetAsync(wout + CNT_OFF, 0, 40960, stream);
    prep_kernel<<<3760, 256, 0, stream>>>(
        (const float*)d_in[2], (const float*)d_in[3], (const float*)d_in[4],
        (const float*)d_in[5], (const float*)d_in[6], (const float*)d_in[7],
        (const float*)d_in[8], (const float*)d_in[9], (const float*)d_in[10],
        (const float*)d_in[11], (const float*)d_in[12], (const float*)d_in[13], wout);
    hist_kernel<<<391, 256, 0, stream>>>(eidx, (int*)(wout + CNT_OFF));
    scan_kernel<<<1, 256, 0, stream>>>((const int*)(wout + CNT_OFF), (int*)(wout + CUR_OFF));
    scatter_kernel<<<391, 256, 0, stream>>>(eidx, (int*)(wout + CUR_OFF), (int*)(wout + PERM_OFF));
    msg_kernel<<<(kEdges + 63) / 64, 256, 0, stream>>>(nf, ea, eidx, wout, agg);
    upd_kernel<<<(kNodes + 31) / 32, 512, 0, stream>>>(nf, wout, agg);
    copy_kernel<<<1563, 256, 0, stream>>>(agg, (float*)d_out);
}